// Round 4
// baseline (48.614 us; speedup 1.0000x reference)
//
#include <hip/hip_runtime.h>

#define DELAY   4410
#define NPAIR   2205      // DELAY/2 float2 lanes per row; row = 17640 B, contiguous
#define NCHUNK  6000
#define FB      0.5f
#define TCH     24        // rows per block -> 250 blocks, each streams 1.06 MB contiguous
#define KLOOK   12        // warm-up lookback: 0.5^12 * |y| ~ 1.5e-3 << 0.126 threshold
#define THREADS 512
#define NJ      4         // 4*512 = 2048 full pairs
#define TAILP   157       // 2205 - 2048 remaining pairs

typedef float v2f __attribute__((ext_vector_type(2)));

__global__ __launch_bounds__(THREADS)
void ReverbModel_67508295958534_kernel(const float* __restrict__ x,
                                       float* __restrict__ y) {
    const int t  = threadIdx.x;
    const int c0 = blockIdx.x * TCH;
    const v2f* __restrict__ x2 = (const v2f*)x;
    v2f* __restrict__ y2 = (v2f*)y;

    // 5 carry pairs per thread (lane-pairs t, t+512, t+1024, t+1536, t+2048)
    float ca[NJ + 1][2] = {};
    const bool tail = (t < TAILP);

    // Warm-up: re-seed carries from the previous KLOOK rows (geometric decay).
    int cstart = c0 - KLOOK;
    if (cstart < 0) cstart = 0;
    for (int c = cstart; c < c0; ++c) {
        size_t rb = (size_t)c * NPAIR + t;
        #pragma unroll
        for (int j = 0; j < NJ; ++j) {
            v2f v = x2[rb + j * THREADS];
            ca[j][0] = v.x + FB * ca[j][0];
            ca[j][1] = v.y + FB * ca[j][1];
        }
        if (tail) {
            v2f v = x2[rb + NJ * THREADS];
            ca[NJ][0] = v.x + FB * ca[NJ][0];
            ca[NJ][1] = v.y + FB * ca[NJ][1];
        }
    }

    // Main: block streams rows [c0, c0+TCH) — fully contiguous flat range.
    #pragma unroll 2
    for (int c = c0; c < c0 + TCH; ++c) {
        size_t rb = (size_t)c * NPAIR + t;
        #pragma unroll
        for (int j = 0; j < NJ; ++j) {
            v2f v = x2[rb + j * THREADS];
            float o0 = v.x + FB * ca[j][0];
            float o1 = v.y + FB * ca[j][1];
            ca[j][0] = o0; ca[j][1] = o1;
            v2f o; o.x = o0; o.y = o1;
            y2[rb + j * THREADS] = o;
        }
        if (tail) {
            v2f v = x2[rb + NJ * THREADS];
            float o0 = v.x + FB * ca[NJ][0];
            float o1 = v.y + FB * ca[NJ][1];
            ca[NJ][0] = o0; ca[NJ][1] = o1;
            v2f o; o.x = o0; o.y = o1;
            y2[rb + NJ * THREADS] = o;
        }
    }
}

extern "C" void kernel_launch(void* const* d_in, const int* in_sizes, int n_in,
                              void* d_out, int out_size, void* d_ws, size_t ws_size,
                              hipStream_t stream) {
    const float* x = (const float*)d_in[0];
    float* y = (float*)d_out;

    dim3 grid(NCHUNK / TCH);   // 250 blocks
    dim3 block(THREADS);
    ReverbModel_67508295958534_kernel<<<grid, block, 0, stream>>>(x, y);
}